// Round 6
// baseline (151.933 us; speedup 1.0000x reference)
//
#include <hip/hip_runtime.h>
#include <math.h>

#pragma clang fp contract(off)

#define BB   8
#define NGT  60
#define LL   21504
#define CC   15
#define KTOP 13
#define BGI  15
#define EPSF 1e-9f
#define NW   (NGT * KTOP)      // 780 winner slots per batch
#define DTILE (BB * LL / 512)  // 336 default-output tiles

typedef unsigned long long u64;

// branchless descending compare-swap: ensures a >= b afterwards
#define CS(a, b) { u64 _hi = (b > a) ? b : a; u64 _lo = (b > a) ? a : b; a = _hi; b = _lo; }

// AABB of rotated box given precomputed trig, replicating reference
// _box_min_max op order. NOTE: NOT a true bounding box of the rotated rect
// (reference quirk); used only for IOU, exactly as the reference uses it.
__device__ __forceinline__ float4 aabb_from_trig(float cx, float cy, float w,
                                                 float h, float cr, float sr) {
    float dx = (w * 0.5f) * cr;
    float dy = (h * 0.5f) * sr;
    float xs[4] = {cx - dx, cx + dx, cx + dx, cx - dx};
    float ys[4] = {cy - dy, cy - dy, cy + dy, cy + dy};
    float mnx = 1e30f, mxx = -1e30f, mny = 1e30f, mxy = -1e30f;
#pragma unroll
    for (int k = 0; k < 4; ++k) {
        float tx = xs[k] - cx, ty = ys[k] - cy;
        float xr = (cx + tx * cr) - ty * sr;
        float yr = (cy + tx * sr) + ty * cr;
        mnx = fminf(mnx, xr); mxx = fmaxf(mxx, xr);
        mny = fminf(mny, yr); mxy = fmaxf(mxy, yr);
    }
    return make_float4(mnx, mxx, mny, mxy);
}

// sincos f64 (one shared argument reduction), rounded to f32.
__device__ __forceinline__ void trig32(float r, float& cr, float& sr) {
    double s_, c_;
    sincos((double)r, &s_, &c_);
    cr = (float)c_; sr = (float)s_;
}

__device__ __forceinline__ float iou_pair(float4 g, float a1, float4 p, float a2) {
    float iw = fmaxf(fminf(g.y, p.y) - fmaxf(g.x, p.x), 0.0f);
    float ih = fmaxf(fminf(g.w, p.w) - fmaxf(g.z, p.z), 0.0f);
    float inter = iw * ih;
    float denom = ((a1 + a2) - inter) + EPSF;
    float q = inter / denom;
    return fminf(fmaxf(q, 0.0f), 1.0f);
}

// output region offsets
#define O0 ((size_t)0)
#define O1 ((size_t)BB * LL)
#define O2 (O1 + (size_t)BB * LL * 5)
#define O3 (O2 + (size_t)BB * LL * CC)
#define O4 (O3 + (size_t)BB * LL)

// ---------- kernel 1: topk rows (blocks 0..479) + default outputs (480..815) ----------
// Topk: one 512-thread block per gt row; candidate rect from the TRUE
// bounding box of the rotated inside test; explicit j=0..127 (scale-8 row 0)
// replicates jax.lax.top_k's smallest-index zero-metric fill; scale-8 rect
// starts at row 1 (duplicate-free). Key = (float_bits(v)<<32)|~j.
// Winners stored as 13 raw keys per row (all slots written -> poison-safe,
// no zero-init pass). Zero-metric inside-retest deferred to kernel 2.
// Defaults: bg label, gt0 rbox, idx 0, crowd0 for ALL anchors; scores region
// left zero (harness zeroes the out buffer before the launch).
__global__ __launch_bounds__(512) void topk_defaults_kernel(
        const float* __restrict__ ps,
        const float* __restrict__ pr,
        const int*   __restrict__ labels,
        const float* __restrict__ gt,
        const int*   __restrict__ crowd,
        const float* __restrict__ pad,
        u64* __restrict__ win,
        float* __restrict__ out) {
    __shared__ u64   sk[8 * KTOP];
    __shared__ float sgt[12];
    __shared__ int   slab;
    const int blk = blockIdx.x;
    const int t   = threadIdx.x;

    if (blk >= BB * NGT) {               // ---- defaults branch ----
        const int dblk = blk - BB * NGT;
        const int b  = dblk / (LL / 512);
        const int j0 = (dblk % (LL / 512)) * 512;
        if (t < 5)  sgt[t] = gt[(size_t)b * NGT * 5 + t];   // gt0 rbox
        if (t == 5) sgt[5] = (float)crowd[b * NGT];          // crowd0
        __syncthreads();
        const int p = b * LL + j0 + t;
        out[O0 + p] = (float)BGI;
        out[O3 + p] = 0.0f;
        out[O4 + p] = sgt[5];
        float* o1 = out + O1 + (size_t)(b * LL + j0) * 5;
#pragma unroll
        for (int k = 0; k < 5; ++k) {
            int g = k * 512 + t;
            o1[g] = sgt[g % 5];
        }
        return;
    }

    // ---- topk branch ----
    const int bi = blk;
    if (t == 0) {
        const float* gp = gt + (size_t)bi * 5;
        float gcx = gp[0], gcy = gp[1], gw = gp[2], gh = gp[3], gr = gp[4];
        float cr, sr; trig32(gr, cr, sr);
        float4 gb = aabb_from_trig(gcx, gcy, gw, gh, cr, sr);
        sgt[0] = gb.x; sgt[1] = gb.y; sgt[2] = gb.z; sgt[3] = gb.w;
        sgt[4] = cr;   sgt[5] = sr;
        sgt[6] = gw * gh; sgt[7] = pad[bi];
        sgt[8] = gcx; sgt[9] = gcy; sgt[10] = gw * 0.5f; sgt[11] = gh * 0.5f;
        slab = labels[bi];
    }
    __syncthreads();
    if (sgt[7] == 0.0f) {                // padded gt: write empty winner row
        if (t < KTOP) win[(size_t)bi * KTOP + t] = 0;
        return;
    }
    const int b = bi / NGT;
    const float4 g  = make_float4(sgt[0], sgt[1], sgt[2], sgt[3]);
    const float4 tg = make_float4(sgt[4], sgt[5], sgt[6], 1.0f);
    const float4 gg = make_float4(sgt[8], sgt[9], sgt[10], sgt[11]);
    const float a1 = tg.z;
    const float* srow = ps + (size_t)b * LL * CC + slab;        // stride CC
    const float* prb  = pr + (size_t)b * LL * 5;

    // true AABB of the inside test, +1px fp margin (floor/ceil adds the ring)
    const float ac  = fabsf(tg.x), asn = fabsf(tg.y);
    const float hx  = gg.z * ac + gg.w * asn + 1.0f;
    const float hy  = gg.z * asn + gg.w * ac + 1.0f;
    const float mnx = gg.x - hx, mxx = gg.x + hx;
    const float mny = gg.y - hy, mxy = gg.y + hy;

    int x0a, y0a, nxa, na;
    int x0b, y0b, nxb, nb;
    int x0c, y0c, nxc, nc;
    {   // scale 8 (128x128), rows >= 1 only (row 0 fully covered by explicit)
        int xa = (int)floorf(mnx * 0.125f - 0.5f);
        int xb = (int)ceilf (mxx * 0.125f - 0.5f);
        int ya = (int)floorf(mny * 0.125f - 0.5f);
        int yb = (int)ceilf (mxy * 0.125f - 0.5f);
        xa = xa > 0 ? xa : 0; xb = xb < 127 ? xb : 127;
        ya = ya > 1 ? ya : 1; yb = yb < 127 ? yb : 127;
        x0a = xa; y0a = ya;
        nxa = xb - xa + 1; if (nxa < 0) nxa = 0;
        int ny = yb - ya + 1; if (ny < 0) ny = 0;
        na = nxa * ny;
    }
    {   // scale 16 (64x64)
        int xa = (int)floorf(mnx * 0.0625f - 0.5f);
        int xb = (int)ceilf (mxx * 0.0625f - 0.5f);
        int ya = (int)floorf(mny * 0.0625f - 0.5f);
        int yb = (int)ceilf (mxy * 0.0625f - 0.5f);
        xa = xa > 0 ? xa : 0; xb = xb < 63 ? xb : 63;
        ya = ya > 0 ? ya : 0; yb = yb < 63 ? yb : 63;
        x0b = xa; y0b = ya;
        nxb = xb - xa + 1; if (nxb < 0) nxb = 0;
        int ny = yb - ya + 1; if (ny < 0) ny = 0;
        nb = nxb * ny;
    }
    {   // scale 32 (32x32)
        int xa = (int)floorf(mnx * 0.03125f - 0.5f);
        int xb = (int)ceilf (mxx * 0.03125f - 0.5f);
        int ya = (int)floorf(mny * 0.03125f - 0.5f);
        int yb = (int)ceilf (mxy * 0.03125f - 0.5f);
        xa = xa > 0 ? xa : 0; xb = xb < 31 ? xb : 31;
        ya = ya > 0 ? ya : 0; yb = yb < 31 ? yb : 31;
        x0c = xa; y0c = ya;
        nxc = xb - xa + 1; if (nxc < 0) nxc = 0;
        int ny = yb - ya + 1; if (ny < 0) ny = 0;
        nc = nxc * ny;
    }
    const int Ta = 128 + na;
    const int Tb = Ta + nb;
    const int Tc = Tb + nc;

    u64 k0 = 0, k1 = 0, k2 = 0, k3 = 0, k4 = 0, k5 = 0, k6 = 0,
        k7 = 0, k8 = 0, k9 = 0, k10 = 0, k11 = 0, k12 = 0;

    for (int e = t; e < Tc; e += 512) {
        int j; float ax, ay;
        if (e < 128) {                   // scale-8 row 0: zero-fill + positives
            j = e; ax = ((float)e + 0.5f) * 8.0f; ay = 4.0f;
        } else if (e < Ta) {             // scale-8 rows >= 1
            int rr = e - 128;
            int q = rr / nxa, rem = rr - q * nxa;
            int iy = y0a + q, ix = x0a + rem;
            j = (iy << 7) + ix;
            ax = ((float)ix + 0.5f) * 8.0f;
            ay = ((float)iy + 0.5f) * 8.0f;
        } else if (e < Tb) {             // scale 16
            int rr = e - Ta;
            int q = rr / nxb, rem = rr - q * nxb;
            int iy = y0b + q, ix = x0b + rem;
            j = 16384 + (iy << 6) + ix;
            ax = ((float)ix + 0.5f) * 16.0f;
            ay = ((float)iy + 0.5f) * 16.0f;
        } else {                         // scale 32
            int rr = e - Tb;
            int q = rr / nxc, rem = rr - q * nxc;
            int iy = y0c + q, ix = x0c + rem;
            j = 20480 + (iy << 5) + ix;
            ax = ((float)ix + 0.5f) * 32.0f;
            ay = ((float)iy + 0.5f) * 32.0f;
        }
        float dx = ax - gg.x, dy = ay - gg.y;
        float xl = dx * tg.x + dy * tg.y;
        float yl = dy * tg.x - dx * tg.y;
        bool ing = (fabsf(xl) <= gg.z) && (fabsf(yl) <= gg.w);
        float v = 0.0f;
        if (ing) {
            const float* pp = prb + (size_t)j * 5;
            float pcx = pp[0], pcy = pp[1], pw = pp[2], ph = pp[3], prr = pp[4];
            float pcr, psr; trig32(prr, pcr, psr);
            float4 p = aabb_from_trig(pcx, pcy, pw, ph, pcr, psr);
            float a2 = pw * ph;
            float iou = iou_pair(g, a1, p, a2);
            float i2 = iou * iou;
            v = srow[(size_t)j * CC] * (i2 * i2 * i2);
        }
        u64 key = ((u64)__float_as_uint(v) << 32) | (unsigned)(~j);
        if (key > k12) {                 // insert + bubble (branchless chain)
            k12 = key;
            CS(k11, k12); CS(k10, k11); CS(k9, k10); CS(k8, k9);
            CS(k7, k8);   CS(k6, k7);   CS(k5, k6);  CS(k4, k5);
            CS(k3, k4);   CS(k2, k3);   CS(k1, k2);  CS(k0, k1);
        }
    }

    // per-wave 13-round butterfly merge -> LDS
    const int lane = t & 63;
    const int wv   = t >> 6;
    for (int r = 0; r < KTOP; ++r) {
        u64 ov = k0;
#pragma unroll
        for (int off = 32; off > 0; off >>= 1) {
            u64 v2 = __shfl_xor(ov, off, 64);
            if (v2 > ov) ov = v2;
        }
        if (ov == 0) {                   // wave exhausted (uniform)
            if (lane == 0)
                for (int rr = r; rr < KTOP; ++rr) sk[wv * KTOP + rr] = 0;
            break;
        }
        if (lane == 0) sk[wv * KTOP + r] = ov;
        if (k0 == ov) {                  // keys unique -> exactly one lane pops
            k0 = k1; k1 = k2; k2 = k3; k3 = k4; k4 = k5; k5 = k6; k6 = k7;
            k7 = k8; k8 = k9; k9 = k10; k10 = k11; k11 = k12; k12 = 0;
        }
    }
    __syncthreads();

    // wave 0: merge 8x13; lane r captures round-r winner; store raw keys
    if (t < 64) {
        u64 ka = sk[t];
        u64 kb = (t < 8 * KTOP - 64) ? sk[64 + t] : 0;
        u64 mywin = 0;
        for (int r = 0; r < KTOP; ++r) {
            u64 ov = ka > kb ? ka : kb;
#pragma unroll
            for (int off = 32; off > 0; off >>= 1) {
                u64 v2 = __shfl_xor(ov, off, 64);
                if (v2 > ov) ov = v2;
            }
            if (ov == 0) break;          // uniform
            if (t == r) mywin = ov;      // lane r owns round-r winner
            if (ka == ov) ka = 0;
            else if (kb == ov) kb = 0;
        }
        if (t < KTOP) win[(size_t)bi * KTOP + t] = mywin;  // all slots written
    }
}

// ---------- kernel 2: per-batch claim resolution + sparse output overwrite ----------
// One block per batch. Validates zero-metric winners (inside retest), counts
// multiplicity (= mask_positive_sum), resolves single vs multi claims,
// recomputes iou/metric with the identical op sequence, reduces per-gt
// maxM/maxI in LDS, then overwrites outputs for the <=780 claimed anchors.
__global__ __launch_bounds__(512) void claims_kernel(
        const float* __restrict__ ps,
        const float* __restrict__ pr,
        const int*   __restrict__ labels,
        const float* __restrict__ gt,
        const int*   __restrict__ crowd,
        const u64*   __restrict__ win,
        float* __restrict__ out) {
    __shared__ float4 sB[NGT];           // reference "AABB" (IOU only)
    __shared__ float4 sG[NGT];           // gcx, gcy, w/2, h/2
    __shared__ float2 sT[NGT];           // cos, sin
    __shared__ float  sA[NGT];           // area
    __shared__ int    sL[NGT], sC[NGT];
    __shared__ int    sj[NW];
    __shared__ unsigned smaxM[NGT], smaxI[NGT];
    const int b = blockIdx.x;
    const int t = threadIdx.x;

    if (t < NGT) {
        const float* gp = gt + (size_t)(b * NGT + t) * 5;
        float gcx = gp[0], gcy = gp[1], gw = gp[2], gh = gp[3], gr = gp[4];
        float cr, sr; trig32(gr, cr, sr);
        sB[t] = aabb_from_trig(gcx, gcy, gw, gh, cr, sr);
        sG[t] = make_float4(gcx, gcy, gw * 0.5f, gh * 0.5f);
        sT[t] = make_float2(cr, sr);
        sA[t] = gw * gh;
        sL[t] = labels[b * NGT + t];
        sC[t] = crowd[b * NGT + t];
        smaxM[t] = 0u; smaxI[t] = 0u;
    }
    __syncthreads();

    // load + validate winner slots
    for (int s = t; s < NW; s += 512) {
        u64 k = win[(size_t)b * NW + s];
        int jj = -1;
        if (k != 0) {
            unsigned vb = (unsigned)(k >> 32);
            int j = (int)(~(unsigned)k);
            bool in = (vb != 0);         // v > 0 implies in_gts
            if (!in) {                   // zero-metric pick: inside retest
                int gidx = s / KTOP;
                int bas, gsh; float scf;
                if (j < 16384)      { bas = 0;     gsh = 7; scf = 8.0f; }
                else if (j < 20480) { bas = 16384; gsh = 6; scf = 16.0f; }
                else                { bas = 20480; gsh = 5; scf = 32.0f; }
                int rel = j - bas;
                int iy = rel >> gsh, ix = rel & ((1 << gsh) - 1);
                float ax = ((float)ix + 0.5f) * scf;
                float ay = ((float)iy + 0.5f) * scf;
                float dx = ax - sG[gidx].x, dy = ay - sG[gidx].y;
                float xl = dx * sT[gidx].x + dy * sT[gidx].y;
                float yl = dy * sT[gidx].x - dx * sT[gidx].y;
                in = (fabsf(xl) <= sG[gidx].z) && (fabsf(yl) <= sG[gidx].w);
            }
            if (in) jj = j;
        }
        sj[s] = jj;
    }
    __syncthreads();

    // resolve owned slots (slot A = t, slot B = t+512); first occurrence only
    int jA = -1, aA = 0; float mA = 0.0f;
    int jB = -1, aB = 0; float mB = 0.0f;
#pragma unroll
    for (int it = 0; it < 2; ++it) {
        int s = t + it * 512;
        if (s >= NW) break;
        int j = sj[s];
        if (j < 0) continue;
        int cntj = 0, first = NW;
        for (int s2 = 0; s2 < NW; ++s2)       // uniform index -> LDS broadcast
            if (sj[s2] == j) { ++cntj; if (s2 < first) first = s2; }
        if (first != s) continue;             // duplicate handled by first slot
        const float* pp = pr + (size_t)(b * LL + j) * 5;
        float pcx = pp[0], pcy = pp[1], pw = pp[2], ph = pp[3], prr = pp[4];
        float pcr, psr; trig32(prr, pcr, psr);
        float4 pb = aabb_from_trig(pcx, pcy, pw, ph, pcr, psr);
        float a2 = pw * ph;
        int a; float iouv;
        if (cntj == 1) {
            a = s / KTOP;                     // the single claimant
            iouv = iou_pair(sB[a], sA[a], pb, a2);
        } else {                              // multi-claim: argmax IOU, all gts
            float best = -1.0f; int bix = 0;
            for (int i = 0; i < NGT; ++i) {
                float v = iou_pair(sB[i], sA[i], pb, a2);
                if (v > best) { best = v; bix = i; }  // ties -> lowest index
            }
            a = bix; iouv = best;
        }
        float sc = ps[(size_t)(b * LL + j) * CC + sL[a]];
        float i2 = iouv * iouv;
        float m = sc * (i2 * i2 * i2);
        atomicMax(&smaxM[a], __float_as_uint(m));
        atomicMax(&smaxI[a], __float_as_uint(iouv));
        if (it == 0) { jA = j; aA = a; mA = m; }
        else         { jB = j; aB = a; mB = m; }
    }
    __syncthreads();

    // write outputs for owned resolved anchors
#pragma unroll
    for (int it = 0; it < 2; ++it) {
        int j = (it == 0) ? jA : jB;
        if (j < 0) continue;
        int a   = (it == 0) ? aA : aB;
        float m = (it == 0) ? mA : mB;
        size_t p = (size_t)b * LL + j;
        out[O0 + p] = (float)sL[a];
        out[O3 + p] = (float)a;
        out[O4 + p] = (float)sC[a];
        const float* gb = gt + (size_t)(b * NGT + a) * 5;
        float* o1 = out + O1 + p * 5;
#pragma unroll
        for (int k = 0; k < 5; ++k) o1[k] = gb[k];
        if (sC[a] == 0) {
            float mm = __uint_as_float(smaxM[a]);
            float mi = __uint_as_float(smaxI[a]);
            float per = m / (mm + EPSF) * mi;
            out[O2 + p * CC + sL[a]] = per;   // sparse one-hot write
        }
    }
}

extern "C" void kernel_launch(void* const* d_in, const int* in_sizes, int n_in,
                              void* d_out, int out_size, void* d_ws, size_t ws_size,
                              hipStream_t stream) {
    const float* pred_scores = (const float*)d_in[0];
    const float* pred_rboxes = (const float*)d_in[1];
    // d_in[2] = anchor_points (recomputed analytically; exact in fp32)
    const int*   gt_labels   = (const int*)d_in[3];
    const float* gt_bboxes   = (const float*)d_in[4];
    // d_in[5] = gt_poses (unused)
    const int*   gt_crowd    = (const int*)d_in[6];
    const float* pad_gt      = (const float*)d_in[7];
    float* out = (float*)d_out;

    u64* win = (u64*)d_ws;   // BB*NGT*KTOP keys; every slot written each launch

    topk_defaults_kernel<<<dim3(BB * NGT + DTILE), dim3(512), 0, stream>>>(
        pred_scores, pred_rboxes, gt_labels, gt_bboxes, gt_crowd, pad_gt,
        win, out);
    claims_kernel<<<dim3(BB), dim3(512), 0, stream>>>(
        pred_scores, pred_rboxes, gt_labels, gt_bboxes, gt_crowd, win, out);
}

// Round 9
// 120.915 us; speedup vs baseline: 1.2565x; 1.2565x over previous
//
#include <hip/hip_runtime.h>
#include <math.h>

#pragma clang fp contract(off)

#define BB   8
#define NGT  60
#define LL   21504
#define CC   15
#define KTOP 13
#define BGI  15
#define EPSF 1e-9f

typedef unsigned long long u64;

// branchless descending compare-swap: ensures a >= b afterwards
#define CS(a, b) { u64 _hi = (b > a) ? b : a; u64 _lo = (b > a) ? a : b; a = _hi; b = _lo; }

// AABB of rotated box, replicating reference _box_min_max op order.
// NOTE: NOT a true bounding box of the rotated rect (reference quirk);
// used only for IOU, exactly as the reference uses it.
// sincos (one shared argument reduction) instead of cos+sin: <=2 ulp f64
// difference -> identical after f32 rounding except with prob ~2^-29.
__device__ __forceinline__ float4 rbox_aabb(float cx, float cy, float w, float h, float r) {
    double s_, c_;
    sincos((double)r, &s_, &c_);
    float cr = (float)c_;
    float sr = (float)s_;
    float dx = (w * 0.5f) * cr;
    float dy = (h * 0.5f) * sr;
    float xs[4] = {cx - dx, cx + dx, cx + dx, cx - dx};
    float ys[4] = {cy - dy, cy - dy, cy + dy, cy + dy};
    float mnx = 1e30f, mxx = -1e30f, mny = 1e30f, mxy = -1e30f;
#pragma unroll
    for (int k = 0; k < 4; ++k) {
        float tx = xs[k] - cx, ty = ys[k] - cy;
        float xr = (cx + tx * cr) - ty * sr;
        float yr = (cy + tx * sr) + ty * cr;
        mnx = fminf(mnx, xr); mxx = fmaxf(mxx, xr);
        mny = fminf(mny, yr); mxy = fmaxf(mxy, yr);
    }
    return make_float4(mnx, mxx, mny, mxy);
}

__device__ __forceinline__ float iou_pair(float4 g, float a1, float4 p, float a2) {
    float iw = fmaxf(fminf(g.y, p.y) - fmaxf(g.x, p.x), 0.0f);
    float ih = fmaxf(fminf(g.w, p.w) - fmaxf(g.z, p.z), 0.0f);
    float inter = iw * ih;
    float denom = ((a1 + a2) - inter) + EPSF;
    float q = inter / denom;
    return fminf(fmaxf(q, 0.0f), 1.0f);
}

// ---------- prep: pred boxes (LDS-coalesced), gt state, zero-init ----------
__global__ __launch_bounds__(256) void prep_kernel(
        const float* __restrict__ pr,
        const float* __restrict__ gt,
        const float* __restrict__ pad,
        float4* __restrict__ pbox,
        float* __restrict__ parea,
        float4* __restrict__ gbox,
        float4* __restrict__ gtrig,
        float4* __restrict__ ggeom,
        int* __restrict__ cnt,
        int* __restrict__ claim,
        unsigned* __restrict__ maxM,
        unsigned* __restrict__ maxI) {
    __shared__ float lds[5 * 257];
    const int t = threadIdx.x;
    const int b = blockIdx.x / (LL / 256);
    const int j0 = (blockIdx.x % (LL / 256)) * 256;
    const int i = blockIdx.x * 256 + t;

    const float* prb = pr + (size_t)(b * LL + j0) * 5;
#pragma unroll
    for (int k = 0; k < 5; ++k) {
        int g = k * 256 + t;
        lds[(g % 5) * 257 + g / 5] = prb[g];
    }
    __syncthreads();
    float cx = lds[0 * 257 + t], cy = lds[1 * 257 + t];
    float w  = lds[2 * 257 + t], h  = lds[3 * 257 + t], r = lds[4 * 257 + t];
    pbox[i]  = rbox_aabb(cx, cy, w, h, r);
    parea[i] = w * h;

    cnt[i] = 0; claim[i] = 0;
    if (i < BB * NGT) {
        float gcx = gt[i * 5 + 0], gcy = gt[i * 5 + 1];
        float gw  = gt[i * 5 + 2], gh  = gt[i * 5 + 3], gr = gt[i * 5 + 4];
        gbox[i] = rbox_aabb(gcx, gcy, gw, gh, gr);
        double gs_, gc_;
        sincos((double)gr, &gs_, &gc_);
        gtrig[i] = make_float4((float)gc_, (float)gs_, gw * gh, pad[i]);
        ggeom[i] = make_float4(gcx, gcy, gw * 0.5f, gh * 0.5f);
        maxM[i] = 0u; maxI[i] = 0u;
    }
}

// ---------- topk: true-AABB-restricted per-gt-row top-13, fused merge+atomics ----------
// One 512-thread block per gt row. Candidate rect is built from the TRUE
// bounding box of the rotated-point inside test (hx = w/2|c| + h/2|s|), NOT
// from gbox (whose reference construction does not bound the box). Explicit
// candidates j=0..127 (full scale-8 row 0) replicate jax.lax.top_k's
// smallest-index zero-metric fill exactly; the scale-8 rect starts at row 1
// so enumeration is structurally duplicate-free.
// Key = (float_bits(v) << 32) | ~j  -> (value desc, index asc) = top_k order.
__global__ __launch_bounds__(512) void topk_kernel(
        const float* __restrict__ ps,
        const int* __restrict__ labels,
        const float4* __restrict__ pbox,
        const float* __restrict__ parea,
        const float4* __restrict__ gbox,
        const float4* __restrict__ gtrig,
        const float4* __restrict__ ggeom,
        int* __restrict__ cnt,
        int* __restrict__ claim) {
    __shared__ u64 sk[8 * KTOP];
    const int bi = blockIdx.x;
    float4 tg = gtrig[bi];
    if (tg.w == 0.0f) return;            // padded gt (uniform per block)
    const int b = bi / NGT, gi = bi % NGT;
    float4 g  = gbox[bi];                // reference "AABB" (IOU only)
    float4 gg = ggeom[bi];
    const float a1 = tg.z;
    const float*  srow = ps + (size_t)b * LL * CC + labels[bi];  // stride CC
    const float4* pb   = pbox + (size_t)b * LL;
    const float*  pa   = parea + (size_t)b * LL;

    // true AABB of the inside test, +1px fp margin (floor/ceil adds the ring)
    const float ac  = fabsf(tg.x), asn = fabsf(tg.y);
    const float hx  = gg.z * ac + gg.w * asn + 1.0f;
    const float hy  = gg.z * asn + gg.w * ac + 1.0f;
    const float mnx = gg.x - hx, mxx = gg.x + hx;
    const float mny = gg.y - hy, mxy = gg.y + hy;

    int x0a, y0a, nxa, na;
    int x0b, y0b, nxb, nb;
    int x0c, y0c, nxc, nc;
    {   // scale 8 (128x128), rows >= 1 only (row 0 fully covered by explicit)
        int xa = (int)floorf(mnx * 0.125f - 0.5f);
        int xb = (int)ceilf (mxx * 0.125f - 0.5f);
        int ya = (int)floorf(mny * 0.125f - 0.5f);
        int yb = (int)ceilf (mxy * 0.125f - 0.5f);
        xa = xa > 0 ? xa : 0; xb = xb < 127 ? xb : 127;
        ya = ya > 1 ? ya : 1; yb = yb < 127 ? yb : 127;
        x0a = xa; y0a = ya;
        nxa = xb - xa + 1; if (nxa < 0) nxa = 0;
        int ny = yb - ya + 1; if (ny < 0) ny = 0;
        na = nxa * ny;
    }
    {   // scale 16 (64x64)
        int xa = (int)floorf(mnx * 0.0625f - 0.5f);
        int xb = (int)ceilf (mxx * 0.0625f - 0.5f);
        int ya = (int)floorf(mny * 0.0625f - 0.5f);
        int yb = (int)ceilf (mxy * 0.0625f - 0.5f);
        xa = xa > 0 ? xa : 0; xb = xb < 63 ? xb : 63;
        ya = ya > 0 ? ya : 0; yb = yb < 63 ? yb : 63;
        x0b = xa; y0b = ya;
        nxb = xb - xa + 1; if (nxb < 0) nxb = 0;
        int ny = yb - ya + 1; if (ny < 0) ny = 0;
        nb = nxb * ny;
    }
    {   // scale 32 (32x32)
        int xa = (int)floorf(mnx * 0.03125f - 0.5f);
        int xb = (int)ceilf (mxx * 0.03125f - 0.5f);
        int ya = (int)floorf(mny * 0.03125f - 0.5f);
        int yb = (int)ceilf (mxy * 0.03125f - 0.5f);
        xa = xa > 0 ? xa : 0; xb = xb < 31 ? xb : 31;
        ya = ya > 0 ? ya : 0; yb = yb < 31 ? yb : 31;
        x0c = xa; y0c = ya;
        nxc = xb - xa + 1; if (nxc < 0) nxc = 0;
        int ny = yb - ya + 1; if (ny < 0) ny = 0;
        nc = nxc * ny;
    }
    const int Ta = 128 + na;
    const int Tb = Ta + nb;
    const int Tc = Tb + nc;

    u64 k0 = 0, k1 = 0, k2 = 0, k3 = 0, k4 = 0, k5 = 0, k6 = 0,
        k7 = 0, k8 = 0, k9 = 0, k10 = 0, k11 = 0, k12 = 0;

    for (int e = threadIdx.x; e < Tc; e += 512) {
        int j; float ax, ay;
        if (e < 128) {                   // scale-8 row 0: zero-fill + positives
            j = e; ax = ((float)e + 0.5f) * 8.0f; ay = 4.0f;
        } else if (e < Ta) {             // scale-8 rows >= 1
            int rr = e - 128;
            int q = rr / nxa, rem = rr - q * nxa;
            int iy = y0a + q, ix = x0a + rem;
            j = (iy << 7) + ix;
            ax = ((float)ix + 0.5f) * 8.0f;
            ay = ((float)iy + 0.5f) * 8.0f;
        } else if (e < Tb) {             // scale 16
            int rr = e - Ta;
            int q = rr / nxb, rem = rr - q * nxb;
            int iy = y0b + q, ix = x0b + rem;
            j = 16384 + (iy << 6) + ix;
            ax = ((float)ix + 0.5f) * 16.0f;
            ay = ((float)iy + 0.5f) * 16.0f;
        } else {                         // scale 32
            int rr = e - Tb;
            int q = rr / nxc, rem = rr - q * nxc;
            int iy = y0c + q, ix = x0c + rem;
            j = 20480 + (iy << 5) + ix;
            ax = ((float)ix + 0.5f) * 32.0f;
            ay = ((float)iy + 0.5f) * 32.0f;
        }
        float dx = ax - gg.x, dy = ay - gg.y;
        float xl = dx * tg.x + dy * tg.y;
        float yl = dy * tg.x - dx * tg.y;
        bool ing = (fabsf(xl) <= gg.z) && (fabsf(yl) <= gg.w);
        float v = 0.0f;
        if (ing) {
            float4 p = pb[j];
            float a2 = pa[j];
            float iou = iou_pair(g, a1, p, a2);
            float i2 = iou * iou;
            v = srow[(size_t)j * CC] * (i2 * i2 * i2);
        }
        u64 key = ((u64)__float_as_uint(v) << 32) | (unsigned)(~j);
        if (key > k12) {                 // insert + bubble (branchless chain)
            k12 = key;
            CS(k11, k12); CS(k10, k11); CS(k9, k10); CS(k8, k9);
            CS(k7, k8);   CS(k6, k7);   CS(k5, k6);  CS(k4, k5);
            CS(k3, k4);   CS(k2, k3);   CS(k1, k2);  CS(k0, k1);
        }
    }

    // per-wave 13-round butterfly merge -> LDS
    const int lane = threadIdx.x & 63;
    const int wv   = threadIdx.x >> 6;
    for (int r = 0; r < KTOP; ++r) {
        u64 ov = k0;
#pragma unroll
        for (int off = 32; off > 0; off >>= 1) {
            u64 v2 = __shfl_xor(ov, off, 64);
            if (v2 > ov) ov = v2;
        }
        if (ov == 0) {                   // wave exhausted (uniform)
            if (lane == 0)
                for (int rr = r; rr < KTOP; ++rr) sk[wv * KTOP + rr] = 0;
            break;
        }
        if (lane == 0) sk[wv * KTOP + r] = ov;
        if (k0 == ov) {                  // keys unique -> exactly one lane pops
            k0 = k1; k1 = k2; k2 = k3; k3 = k4; k4 = k5; k5 = k6; k6 = k7;
            k7 = k8; k8 = k9; k9 = k10; k10 = k11; k11 = k12; k12 = 0;
        }
    }
    __syncthreads();

    // wave 0: merge 8x13; lane r captures round-r winner, atomics in parallel
    if (threadIdx.x < 64) {
        const int t = threadIdx.x;
        u64 ka = sk[t];
        u64 kb = (t < 8 * KTOP - 64) ? sk[64 + t] : 0;
        u64 mywin = 0;
        for (int r = 0; r < KTOP; ++r) {
            u64 ov = ka > kb ? ka : kb;
#pragma unroll
            for (int off = 32; off > 0; off >>= 1) {
                u64 v2 = __shfl_xor(ov, off, 64);
                if (v2 > ov) ov = v2;
            }
            if (ov == 0) break;          // uniform
            if (t == r) mywin = ov;      // lane r owns round-r winner
            if (ka == ov) ka = 0;
            else if (kb == ov) kb = 0;
        }
        if (mywin != 0) {
            unsigned vb = (unsigned)(mywin >> 32);
            int j = (int)(~(unsigned)mywin);
            bool in = (vb != 0);         // v > 0 implies in_gts
            if (!in) {                   // zero-metric pick: explicit retest
                int bas, gsh; float scf;
                if (j < 16384)      { bas = 0;     gsh = 7; scf = 8.0f; }
                else if (j < 20480) { bas = 16384; gsh = 6; scf = 16.0f; }
                else                { bas = 20480; gsh = 5; scf = 32.0f; }
                int rel = j - bas;
                int iy = rel >> gsh, ix = rel & ((1 << gsh) - 1);
                float ax = ((float)ix + 0.5f) * scf;
                float ay = ((float)iy + 0.5f) * scf;
                float dx = ax - gg.x, dy = ay - gg.y;
                float xl = dx * tg.x + dy * tg.y;
                float yl = dy * tg.x - dx * tg.y;
                in = (fabsf(xl) <= gg.z) && (fabsf(yl) <= gg.w);
            }
            if (in) {
                atomicAdd(&cnt[b * LL + j], 1);
                atomicMax(&claim[b * LL + j], gi);
            }
        }
    }
}

// ---------- resolve: assign one gt (or none) per anchor; per-gt maxes ----------
__global__ void resolve_kernel(const float* __restrict__ ps,
                               const int* __restrict__ labels,
                               const float4* __restrict__ pbox,
                               const float* __restrict__ parea,
                               const float4* __restrict__ gbox,
                               const float4* __restrict__ gtrig,
                               const int* __restrict__ cnt,
                               const int* __restrict__ claim,
                               int* __restrict__ assigned,
                               float* __restrict__ aMetric,
                               unsigned* __restrict__ maxM,
                               unsigned* __restrict__ maxI) {
    __shared__ float4 sB[NGT];
    __shared__ float  sA[NGT];
    int b = blockIdx.y, t = threadIdx.x;
    if (t < NGT) { sB[t] = gbox[b * NGT + t]; sA[t] = gtrig[b * NGT + t].z; }
    __syncthreads();
    int j = blockIdx.x * blockDim.x + t;
    if (j >= LL) return;
    int p = b * LL + j;
    int c = cnt[p];
    if (c == 0) { assigned[p] = -1; aMetric[p] = 0.0f; return; }
    float4 pb = pbox[p];
    float a2 = parea[p];
    int a; float iouv;
    if (c == 1) {
        a = claim[p];
        iouv = iou_pair(sB[a], sA[a], pb, a2);
    } else {
        float best = -1.0f; int bi = 0;
        for (int i = 0; i < NGT; ++i) {
            float v = iou_pair(sB[i], sA[i], pb, a2);
            if (v > best) { best = v; bi = i; }       // ties -> lowest index
        }
        a = bi; iouv = best;
    }
    float sc = ps[(size_t)p * CC + labels[b * NGT + a]];  // sparse direct read
    float i2 = iouv * iouv;
    float m = sc * (i2 * i2 * i2);
    assigned[p] = a;
    aMetric[p] = m;
    atomicMax(&maxM[b * NGT + a], __float_as_uint(m));
    atomicMax(&maxI[b * NGT + a], __float_as_uint(iouv));
}

// ---------- finalize: all 5 outputs; strided regions via LDS transpose ----------
__global__ __launch_bounds__(256) void finalize_kernel(
        const float* __restrict__ gt,
        const int* __restrict__ labels,
        const int* __restrict__ crowd,
        const int* __restrict__ assigned,
        const float* __restrict__ aMetric,
        const unsigned* __restrict__ maxM,
        const unsigned* __restrict__ maxI,
        float* __restrict__ out) {
    __shared__ float lds[CC * 257];
    const int t = threadIdx.x;
    const int b = blockIdx.x / (LL / 256);
    const int j0 = (blockIdx.x % (LL / 256)) * 256;
    const int p = blockIdx.x * 256 + t;
    const size_t O0 = 0;
    const size_t O1 = (size_t)BB * LL;
    const size_t O2 = O1 + (size_t)BB * LL * 5;
    const size_t O3 = O2 + (size_t)BB * LL * CC;
    const size_t O4 = O3 + (size_t)BB * LL;

    int a = assigned[p];
    bool pos = (a >= 0);
    int idx = pos ? a : 0;
    int lab = labels[b * NGT + idx];
    int cw  = crowd[b * NGT + idx];
    out[O0 + p] = pos ? (float)lab : (float)BGI;
    out[O3 + p] = (float)idx;
    out[O4 + p] = (float)cw;
    float per = 0.0f;
    if (pos) {
        float mm = __uint_as_float(maxM[b * NGT + a]);
        float mi = __uint_as_float(maxI[b * NGT + a]);
        per = aMetric[p] / (mm + EPSF) * mi;
    }

    // assigned_scores (stride-15) via LDS transpose
    float keep = (pos && cw == 0) ? per : 0.0f;
#pragma unroll
    for (int c = 0; c < CC; ++c)
        lds[c * 257 + t] = (c == lab) ? keep : 0.0f;
    __syncthreads();
    float* o2 = out + O2 + (size_t)(b * LL + j0) * CC;
#pragma unroll
    for (int k = 0; k < CC; ++k) {
        int g = k * 256 + t;
        o2[g] = lds[(g % CC) * 257 + g / CC];
    }
    __syncthreads();

    // assigned_rboxes (stride-5) via LDS transpose
    const float* gb = gt + (size_t)(b * NGT + idx) * 5;
#pragma unroll
    for (int k = 0; k < 5; ++k)
        lds[k * 257 + t] = gb[k];
    __syncthreads();
    float* o1 = out + O1 + (size_t)(b * LL + j0) * 5;
#pragma unroll
    for (int k = 0; k < 5; ++k) {
        int g = k * 256 + t;
        o1[g] = lds[(g % 5) * 257 + g / 5];
    }
}

extern "C" void kernel_launch(void* const* d_in, const int* in_sizes, int n_in,
                              void* d_out, int out_size, void* d_ws, size_t ws_size,
                              hipStream_t stream) {
    const float* pred_scores = (const float*)d_in[0];
    const float* pred_rboxes = (const float*)d_in[1];
    // d_in[2] = anchor_points (recomputed analytically; exact in fp32)
    const int*   gt_labels   = (const int*)d_in[3];
    const float* gt_bboxes   = (const float*)d_in[4];
    // d_in[5] = gt_poses (unused)
    const int*   gt_crowd    = (const int*)d_in[6];
    const float* pad_gt      = (const float*)d_in[7];
    float* out = (float*)d_out;

    char* ws = (char*)d_ws;
    size_t off = 0;
    auto alloc = [&](size_t bytes) {
        void* pp = ws + off;
        off += (bytes + 255) & ~(size_t)255;
        return pp;
    };
    float4* pbox  = (float4*)alloc((size_t)BB * LL * 16);
    float*  parea = (float*)alloc((size_t)BB * LL * 4);
    float4* gbox  = (float4*)alloc((size_t)BB * NGT * 16);
    float4* gtrig = (float4*)alloc((size_t)BB * NGT * 16);
    float4* ggeom = (float4*)alloc((size_t)BB * NGT * 16);
    int* cnt        = (int*)alloc((size_t)BB * LL * 4);
    int* claim      = (int*)alloc((size_t)BB * LL * 4);
    unsigned* maxM  = (unsigned*)alloc((size_t)BB * NGT * 4);
    unsigned* maxI  = (unsigned*)alloc((size_t)BB * NGT * 4);
    int*   assigned = (int*)alloc((size_t)BB * LL * 4);
    float* aMetric  = (float*)alloc((size_t)BB * LL * 4);

    prep_kernel<<<dim3(BB * LL / 256), dim3(256), 0, stream>>>(
        pred_rboxes, gt_bboxes, pad_gt,
        pbox, parea, gbox, gtrig, ggeom, cnt, claim, maxM, maxI);
    topk_kernel<<<dim3(BB * NGT), dim3(512), 0, stream>>>(
        pred_scores, gt_labels, pbox, parea, gbox, gtrig, ggeom, cnt, claim);
    resolve_kernel<<<dim3(LL / 256, BB), dim3(256), 0, stream>>>(
        pred_scores, gt_labels, pbox, parea, gbox, gtrig, cnt, claim,
        assigned, aMetric, maxM, maxI);
    finalize_kernel<<<dim3(BB * LL / 256), dim3(256), 0, stream>>>(
        gt_bboxes, gt_labels, gt_crowd, assigned, aMetric, maxM, maxI, out);
}